// Round 3
// baseline (858.489 us; speedup 1.0000x reference)
//
#include <hip/hip_runtime.h>

#define S_LEN 512
#define BSZ 8
#define NH 8
#define HD 64
#define IN_DIM 512
#define PROJ 2576   // NH*(5*HD+2)
#define SEG 322     // per-head: 5*64+2
#define AST 352     // act row stride f32: q64,k64,rk64,v64,rv64,beta,rbeta,pad -> 8 rows = 11*1024B
#define CHUNK 8
#define NCH 64      // 512/CHUNK
#define CB (CHUNK * AST * 4)  // 11264 bytes per chunk

typedef __attribute__((ext_vector_type(8))) __bf16 bf16x8;
typedef __attribute__((ext_vector_type(4))) float f32x4;
typedef __attribute__((ext_vector_type(2))) float f32x2;

typedef union { f32x4 v4; f32x2 v2[2]; float f[4]; } u4;

static __device__ __forceinline__ unsigned short f2bf(float f) {
  unsigned u = __float_as_uint(f);
  unsigned r = (u + 0x7fffu + ((u >> 16) & 1u)) >> 16;
  return (unsigned short)r;
}
static __device__ __forceinline__ float bf2f(unsigned short s) {
  return __uint_as_float(((unsigned)s) << 16);
}

// packed 2-wide FMA / ADD (compiler does not auto-form VOP3P f32 ops)
static __device__ __forceinline__ f32x2 pk_fma(f32x2 a, f32x2 b, f32x2 c) {
  f32x2 d;
  asm("v_pk_fma_f32 %0, %1, %2, %3" : "=v"(d) : "v"(a), "v"(b), "v"(c));
  return d;
}
static __device__ __forceinline__ f32x2 pk_add(f32x2 a, f32x2 b) {
  f32x2 d;
  asm("v_pk_add_f32 %0, %1, %2" : "=v"(d) : "v"(a), "v"(b));
  return d;
}

static __device__ __forceinline__ void gl_lds16(const void* g, void* l) {
  __builtin_amdgcn_global_load_lds(
      (const __attribute__((address_space(1))) unsigned int*)g,
      (__attribute__((address_space(3))) unsigned int*)l, 16, 0, 0);
}

// ---------------- LayerNorm: x (4096x512 f32) -> normed bf16 ----------------
__global__ __launch_bounds__(256) void ln_kernel(const float* __restrict__ x,
                                                 const float* __restrict__ gamma,
                                                 const float* __restrict__ beta,
                                                 unsigned short* __restrict__ out) {
  int wave = threadIdx.x >> 6, lane = threadIdx.x & 63;
  int row = blockIdx.x * 4 + wave;
  const float* xr = x + (size_t)row * IN_DIM + lane * 8;
  float4 a = *(const float4*)xr;
  float4 b = *(const float4*)(xr + 4);
  float vals[8] = {a.x, a.y, a.z, a.w, b.x, b.y, b.z, b.w};
  float s = 0.f, ss = 0.f;
#pragma unroll
  for (int i = 0; i < 8; i++) { s += vals[i]; ss += vals[i] * vals[i]; }
#pragma unroll
  for (int o = 32; o; o >>= 1) { s += __shfl_xor(s, o); ss += __shfl_xor(ss, o); }
  float mu = s * (1.f / 512.f);
  float var = ss * (1.f / 512.f) - mu * mu;
  float rstd = rsqrtf(var + 1e-5f);
  const float* g = gamma + lane * 8;
  const float* be = beta + lane * 8;
  float4 g1 = *(const float4*)g, g2 = *(const float4*)(g + 4);
  float4 b1 = *(const float4*)be, b2 = *(const float4*)(be + 4);
  float gs[8] = {g1.x, g1.y, g1.z, g1.w, g2.x, g2.y, g2.z, g2.w};
  float bs[8] = {b1.x, b1.y, b1.z, b1.w, b2.x, b2.y, b2.z, b2.w};
  union { unsigned short u[8]; uint4 v; } pk;
#pragma unroll
  for (int i = 0; i < 8; i++) pk.u[i] = f2bf((vals[i] - mu) * rstd * gs[i] + bs[i]);
  *(uint4*)(out + (size_t)row * IN_DIM + lane * 8) = pk.v;
}

// ---------------- generic f32 -> bf16 cast ----------------
__global__ void cast_kernel(const float* __restrict__ in, unsigned short* __restrict__ out, int n) {
  int i = blockIdx.x * blockDim.x + threadIdx.x;
  int st = gridDim.x * blockDim.x;
  for (; i < n; i += st) out[i] = f2bf(in[i]);
}

// ---------------- GEMM: C[m][n] = sum_k A[m][k]*B[n][k] (both bf16, K-contig) ----------------
template <int BF16_OUT, int RESID>
__global__ __launch_bounds__(256) void gemm_bt(const unsigned short* __restrict__ A,
                                               const unsigned short* __restrict__ B,
                                               void* __restrict__ Cout,
                                               const float* __restrict__ resid,
                                               int M, int N, int K) {
  __shared__ __align__(16) unsigned short As[64][40];
  __shared__ __align__(16) unsigned short Bs[64][40];
  int tid = threadIdx.x;
  int lane = tid & 63, wave = tid >> 6;
  int m0 = blockIdx.y * 64, n0 = blockIdx.x * 64;
  int srow = tid >> 2, skq = (tid & 3) * 8;
  const unsigned short* Ap = A + (size_t)(m0 + srow) * K + skq;
  const unsigned short* Bp = B + (size_t)(n0 + srow) * K + skq;
  bool bvalid = (n0 + srow) < N;
  f32x4 zero = {0.f, 0.f, 0.f, 0.f};
  f32x4 acc[4];
#pragma unroll
  for (int nt = 0; nt < 4; nt++) acc[nt] = zero;
  int q = lane >> 4, m16 = lane & 15;
  for (int k0 = 0; k0 < K; k0 += 32) {
    uint4 av = *(const uint4*)(Ap + k0);
    uint4 bz = {0u, 0u, 0u, 0u};
    uint4 bv = bvalid ? *(const uint4*)(Bp + k0) : bz;
    *(uint4*)&As[srow][skq] = av;
    *(uint4*)&Bs[srow][skq] = bv;
    __syncthreads();
    bf16x8 af = *(const bf16x8*)&As[wave * 16 + m16][q * 8];
#pragma unroll
    for (int nt = 0; nt < 4; nt++) {
      bf16x8 bfv = *(const bf16x8*)&Bs[nt * 16 + m16][q * 8];
      acc[nt] = __builtin_amdgcn_mfma_f32_16x16x32_bf16(af, bfv, acc[nt], 0, 0, 0);
    }
    __syncthreads();
  }
  int rbase = q * 4;
#pragma unroll
  for (int nt = 0; nt < 4; nt++) {
#pragma unroll
    for (int rr = 0; rr < 4; rr++) {
      int gm = m0 + wave * 16 + rbase + rr;
      int gn = n0 + nt * 16 + m16;
      if (gn < N) {
        float v = acc[nt][rr];
        if (BF16_OUT) {
          ((unsigned short*)Cout)[(size_t)gm * N + gn] = f2bf(v);
        } else {
          float o = v;
          if (RESID) o += resid[(size_t)gm * N + gn];
          ((float*)Cout)[(size_t)gm * N + gn] = o;
        }
      }
    }
  }
}

// ---------------- parallel activations -> act stream (f32) ----------------
// One wave per (m = t*8+b, h). act[bh][t][AST]:
// [0:64) q softmax, [64:128) k softmax, [128:192) rk softmax,
// [192:256) v, [256:320) rv, [320] sig(beta), [321] sig(rbeta), [322:352) pad.
__global__ __launch_bounds__(256) void act_kernel(const unsigned short* __restrict__ qkvb,
                                                  float* __restrict__ act) {
  int gw = blockIdx.x * 4 + (threadIdx.x >> 6);
  int l = threadIdx.x & 63;
  int m = gw >> 3, hh = gw & 7;
  int t = m >> 3, b = m & 7;
  const unsigned short* src = qkvb + (size_t)m * PROJ + hh * SEG;
  float fq = bf2f(src[l]);
  float fk = bf2f(src[64 + l]);
  float fv = bf2f(src[128 + l]);
  float fr = bf2f(src[192 + l]);
  float frv = bf2f(src[256 + l]);
  float mq = fq, mk = fk, mr = fr;
#pragma unroll
  for (int o = 32; o; o >>= 1) {
    mq = fmaxf(mq, __shfl_xor(mq, o));
    mk = fmaxf(mk, __shfl_xor(mk, o));
    mr = fmaxf(mr, __shfl_xor(mr, o));
  }
  float eq = __expf(fq - mq), ek = __expf(fk - mk), er = __expf(fr - mr);
  float sq = eq, sk = ek, sr = er;
#pragma unroll
  for (int o = 32; o; o >>= 1) {
    sq += __shfl_xor(sq, o);
    sk += __shfl_xor(sk, o);
    sr += __shfl_xor(sr, o);
  }
  int bh = b * 8 + hh;
  float* dst = act + ((size_t)bh * S_LEN + t) * AST;
  dst[l] = eq * __builtin_amdgcn_rcpf(sq);
  dst[64 + l] = ek * __builtin_amdgcn_rcpf(sk);
  dst[128 + l] = er * __builtin_amdgcn_rcpf(sr);
  dst[192 + l] = fv;
  dst[256 + l] = frv;
  if (l < 2) {
    float xv = bf2f(src[320 + l]);
    dst[320 + l] = __builtin_amdgcn_rcpf(1.f + __expf(-xv));
  }
}

// ---------------- scan: SINGLE wave per (b,h), zero barriers ----------------
// One wave does both the W-scan and the R-scan. Lane l owns row l of both W and R
// (f32x2[32] each). z is computed in-register (no zbuf/barrier); the only cross-lane
// traffic is the ehb broadcast, which is same-wave DS-ordered (write-then-read).
// The eh round-trip latency of step t hides under step t+1's W-half.
__global__ __launch_bounds__(64, 1) void scan_kernel(const float* __restrict__ act,
                                                     unsigned short* __restrict__ hs) {
  int bh = blockIdx.x;
  int b = bh >> 3, hh = bh & 7;
  int l = threadIdx.x;

  __shared__ __align__(16) float stage[2][CHUNK * AST];
  __shared__ __align__(16) float ehb[64];

  const char* abase = (const char*)(act + (size_t)bh * S_LEN * AST);

  // stage chunk 0 (single wave: all 11 1-KB slices)
#pragma unroll
  for (int i = 0; i < 11; i++)
    gl_lds16(abase + (size_t)i * 1024 + l * 16, (char*)&stage[0][0] + i * 1024);

  f32x2 W2[32], R2[32];
#pragma unroll
  for (int j = 0; j < 32; j++) {
    W2[j] = (f32x2){0.f, 0.f};
    R2[j] = (f32x2){0.f, 0.f};
  }
  ehb[l] = 1.f;  // softmax(h0=0) numerators -> uniform; sm=64 handled naturally

  unsigned short* hdst = hs + (size_t)b * 512 + hh * 64 + l;

  asm volatile("s_waitcnt vmcnt(0) lgkmcnt(0)" ::: "memory");

  for (int c = 0; c < NCH; c++) {
    int buf = c & 1;
    // issue next chunk's staging; stays in flight across all 8 steps
    if (c + 1 < NCH) {
      const char* nb = abase + (size_t)(c + 1) * CB;
#pragma unroll
      for (int i = 0; i < 11; i++)
        gl_lds16(nb + (size_t)i * 1024 + l * 16, (char*)&stage[buf ^ 1][0] + i * 1024);
    }

#pragma unroll
    for (int s = 0; s < CHUNK; s++) {
      const float* stf = &stage[buf][s * AST];
      const f32x4* st4 = (const f32x4*)stf;
      const f32x2 zz = {0.f, 0.f};

      // ---- W-scan: vold = W.k; fused W += coef*k, z = W.q ----
      u4 kv[16];
      f32x2 a0 = zz, a1 = zz, a2 = zz, a3 = zz;
#pragma unroll
      for (int j = 0; j < 16; j += 2) {
        kv[j].v4 = st4[16 + j];
        kv[j + 1].v4 = st4[17 + j];
        a0 = pk_fma(W2[2 * j], kv[j].v2[0], a0);
        a1 = pk_fma(W2[2 * j + 1], kv[j].v2[1], a1);
        a2 = pk_fma(W2[2 * j + 2], kv[j + 1].v2[0], a2);
        a3 = pk_fma(W2[2 * j + 3], kv[j + 1].v2[1], a3);
      }
      f32x2 vo = pk_add(pk_add(a0, a1), pk_add(a2, a3));
      float vold = vo.x + vo.y;
      float cv = stf[192 + l];
      float coef = stf[320] * (cv - vold);
      f32x2 c2 = {coef, coef};
      a0 = zz; a1 = zz; a2 = zz; a3 = zz;
#pragma unroll
      for (int j = 0; j < 16; j += 2) {
        u4 qA, qB;
        qA.v4 = st4[j];
        qB.v4 = st4[j + 1];
        W2[2 * j] = pk_fma(c2, kv[j].v2[0], W2[2 * j]);
        a0 = pk_fma(W2[2 * j], qA.v2[0], a0);
        W2[2 * j + 1] = pk_fma(c2, kv[j].v2[1], W2[2 * j + 1]);
        a1 = pk_fma(W2[2 * j + 1], qA.v2[1], a1);
        W2[2 * j + 2] = pk_fma(c2, kv[j + 1].v2[0], W2[2 * j + 2]);
        a2 = pk_fma(W2[2 * j + 2], qB.v2[0], a2);
        W2[2 * j + 3] = pk_fma(c2, kv[j + 1].v2[1], W2[2 * j + 3]);
        a3 = pk_fma(W2[2 * j + 3], qB.v2[1], a3);
      }
      vo = pk_add(pk_add(a0, a1), pk_add(a2, a3));
      float z = vo.x + vo.y;

      // ---- R-scan: rvold = R.rk; fused R += rcoef*rk, hp = R.eh, sm = sum(eh) ----
      f32x2 b0 = zz, b1 = zz, b2 = zz, b3 = zz;
#pragma unroll
      for (int j = 0; j < 16; j += 2) {
        kv[j].v4 = st4[32 + j];       // rk reuses kv regs (k dead)
        kv[j + 1].v4 = st4[33 + j];
        b0 = pk_fma(R2[2 * j], kv[j].v2[0], b0);
        b1 = pk_fma(R2[2 * j + 1], kv[j].v2[1], b1);
        b2 = pk_fma(R2[2 * j + 2], kv[j + 1].v2[0], b2);
        b3 = pk_fma(R2[2 * j + 3], kv[j + 1].v2[1], b3);
      }
      f32x2 ro = pk_add(pk_add(b0, b1), pk_add(b2, b3));
      float rvold = ro.x + ro.y;
      float rcv = stf[256 + l];
      float rcoef = stf[321] * (rcv - rvold);
      f32x2 rc2 = {rcoef, rcoef};
      const f32x4* e4 = (const f32x4*)ehb;
      f32x2 s0 = zz, s1 = zz;
      b0 = zz; b1 = zz; b2 = zz; b3 = zz;
#pragma unroll
      for (int j = 0; j < 16; j += 2) {
        u4 eA, eB;
        eA.v4 = e4[j];
        eB.v4 = e4[j + 1];
        R2[2 * j] = pk_fma(rc2, kv[j].v2[0], R2[2 * j]);
        b0 = pk_fma(R2[2 * j], eA.v2[0], b0);
        R2[2 * j + 1] = pk_fma(rc2, kv[j].v2[1], R2[2 * j + 1]);
        b1 = pk_fma(R2[2 * j + 1], eA.v2[1], b1);
        R2[2 * j + 2] = pk_fma(rc2, kv[j + 1].v2[0], R2[2 * j + 2]);
        b2 = pk_fma(R2[2 * j + 2], eB.v2[0], b2);
        R2[2 * j + 3] = pk_fma(rc2, kv[j + 1].v2[1], R2[2 * j + 3]);
        b3 = pk_fma(R2[2 * j + 3], eB.v2[1], b3);
        s0 = pk_add(s0, pk_add(eA.v2[0], eA.v2[1]));
        s1 = pk_add(s1, pk_add(eB.v2[0], eB.v2[1]));
      }
      ro = pk_add(pk_add(b0, b1), pk_add(b2, b3));
      float hp = ro.x + ro.y;
      f32x2 sv = pk_add(s0, s1);
      float sm = sv.x + sv.y;

      float h = z + hp * __builtin_amdgcn_rcpf(sm);
      hdst[(size_t)(c * CHUNK + s) * (BSZ * 512)] = f2bf(h);
      // shift-invariant: exp(h-20) keeps qh = eh/sum exact, guards overflow.
      // same-wave DS ordering makes this visible to next step's e4 reads (no wait).
      ehb[l] = __expf(h - 20.f);
    }

    // chunk boundary: staged loads (11, older) done once <=8 newest (h-stores) remain
    if (c + 1 < NCH) {
      asm volatile("s_waitcnt vmcnt(8)" ::: "memory");
    }
  }
}

extern "C" void kernel_launch(void* const* d_in, const int* in_sizes, int n_in,
                              void* d_out, int out_size, void* d_ws, size_t ws_size,
                              hipStream_t stream) {
  const float* x = (const float*)d_in[0];
  const float* W_slow = (const float*)d_in[1];
  const float* W_out = (const float*)d_in[2];
  const float* gamma = (const float*)d_in[3];
  const float* beta = (const float*)d_in[4];

  char* ws = (char*)d_ws;
  size_t off = 0;
  unsigned short* normed = (unsigned short*)(ws + off); off += (size_t)4096 * 512 * 2;
  unsigned short* Wslow_b = (unsigned short*)(ws + off); off += (size_t)PROJ * 512 * 2;
  unsigned short* Wout_b = (unsigned short*)(ws + off); off += (size_t)512 * 512 * 2;
  unsigned short* qkvb = (unsigned short*)(ws + off); off += (size_t)4096 * PROJ * 2;
  float* act = (float*)(ws + off); off += (size_t)64 * S_LEN * AST * 4;
  unsigned short* hsb = normed;  // normed is dead after gemm1; reuse for hs

  hipLaunchKernelGGL(ln_kernel, dim3(1024), dim3(256), 0, stream, x, gamma, beta, normed);
  hipLaunchKernelGGL(cast_kernel, dim3(512), dim3(256), 0, stream, W_slow, Wslow_b, PROJ * 512);
  hipLaunchKernelGGL(cast_kernel, dim3(256), dim3(256), 0, stream, W_out, Wout_b, 512 * 512);
  hipLaunchKernelGGL((gemm_bt<1, 0>), dim3((PROJ + 63) / 64, 4096 / 64), dim3(256), 0, stream,
                     normed, Wslow_b, (void*)qkvb, (const float*)nullptr, 4096, PROJ, 512);
  hipLaunchKernelGGL(act_kernel, dim3(8192), dim3(256), 0, stream, qkvb, act);
  hipLaunchKernelGGL(scan_kernel, dim3(64), dim3(64), 0, stream, act, hsb);
  hipLaunchKernelGGL((gemm_bt<0, 1>), dim3(512 / 64, 4096 / 64), dim3(256), 0, stream,
                     hsb, Wout_b, d_out, x, 4096, 512, 512);
}

// Round 4
// 404.348 us; speedup vs baseline: 2.1231x; 2.1231x over previous
//
#include <hip/hip_runtime.h>

#define S_LEN 512
#define BSZ 8
#define NH 8
#define HD 64
#define IN_DIM 512
#define PROJ 2576   // NH*(5*HD+2)
#define SEG 322     // per-head: 5*64+2
#define AST 352     // act row stride f32: q64,k64,rk64,v64,rv64,beta,rbeta,pad -> 8 rows = 11*1024B
#define CHUNK 8
#define NCH 64      // 512/CHUNK
#define CB (CHUNK * AST * 4)  // 11264 bytes per chunk

typedef __attribute__((ext_vector_type(8))) __bf16 bf16x8;
typedef __attribute__((ext_vector_type(4))) float f32x4;

static __device__ __forceinline__ unsigned short f2bf(float f) {
  unsigned u = __float_as_uint(f);
  unsigned r = (u + 0x7fffu + ((u >> 16) & 1u)) >> 16;
  return (unsigned short)r;
}
static __device__ __forceinline__ float bf2f(unsigned short s) {
  return __uint_as_float(((unsigned)s) << 16);
}

static __device__ __forceinline__ void gl_lds16(const void* g, void* l) {
  __builtin_amdgcn_global_load_lds(
      (const __attribute__((address_space(1))) unsigned int*)g,
      (__attribute__((address_space(3))) unsigned int*)l, 16, 0, 0);
}

// ---------------- LayerNorm: x (4096x512 f32) -> normed bf16 ----------------
__global__ __launch_bounds__(256) void ln_kernel(const float* __restrict__ x,
                                                 const float* __restrict__ gamma,
                                                 const float* __restrict__ beta,
                                                 unsigned short* __restrict__ out) {
  int wave = threadIdx.x >> 6, lane = threadIdx.x & 63;
  int row = blockIdx.x * 4 + wave;
  const float* xr = x + (size_t)row * IN_DIM + lane * 8;
  float4 a = *(const float4*)xr;
  float4 b = *(const float4*)(xr + 4);
  float vals[8] = {a.x, a.y, a.z, a.w, b.x, b.y, b.z, b.w};
  float s = 0.f, ss = 0.f;
#pragma unroll
  for (int i = 0; i < 8; i++) { s += vals[i]; ss += vals[i] * vals[i]; }
#pragma unroll
  for (int o = 32; o; o >>= 1) { s += __shfl_xor(s, o); ss += __shfl_xor(ss, o); }
  float mu = s * (1.f / 512.f);
  float var = ss * (1.f / 512.f) - mu * mu;
  float rstd = rsqrtf(var + 1e-5f);
  const float* g = gamma + lane * 8;
  const float* be = beta + lane * 8;
  float4 g1 = *(const float4*)g, g2 = *(const float4*)(g + 4);
  float4 b1 = *(const float4*)be, b2 = *(const float4*)(be + 4);
  float gs[8] = {g1.x, g1.y, g1.z, g1.w, g2.x, g2.y, g2.z, g2.w};
  float bs[8] = {b1.x, b1.y, b1.z, b1.w, b2.x, b2.y, b2.z, b2.w};
  union { unsigned short u[8]; uint4 v; } pk;
#pragma unroll
  for (int i = 0; i < 8; i++) pk.u[i] = f2bf((vals[i] - mu) * rstd * gs[i] + bs[i]);
  *(uint4*)(out + (size_t)row * IN_DIM + lane * 8) = pk.v;
}

// ---------------- generic f32 -> bf16 cast ----------------
__global__ void cast_kernel(const float* __restrict__ in, unsigned short* __restrict__ out, int n) {
  int i = blockIdx.x * blockDim.x + threadIdx.x;
  int st = gridDim.x * blockDim.x;
  for (; i < n; i += st) out[i] = f2bf(in[i]);
}

// ---------------- GEMM: C[m][n] = sum_k A[m][k]*B[n][k] (both bf16, K-contig) ----------------
template <int BF16_OUT, int RESID>
__global__ __launch_bounds__(256) void gemm_bt(const unsigned short* __restrict__ A,
                                               const unsigned short* __restrict__ B,
                                               void* __restrict__ Cout,
                                               const float* __restrict__ resid,
                                               int M, int N, int K) {
  __shared__ __align__(16) unsigned short As[64][40];
  __shared__ __align__(16) unsigned short Bs[64][40];
  int tid = threadIdx.x;
  int lane = tid & 63, wave = tid >> 6;
  int m0 = blockIdx.y * 64, n0 = blockIdx.x * 64;
  int srow = tid >> 2, skq = (tid & 3) * 8;
  const unsigned short* Ap = A + (size_t)(m0 + srow) * K + skq;
  const unsigned short* Bp = B + (size_t)(n0 + srow) * K + skq;
  bool bvalid = (n0 + srow) < N;
  f32x4 zero = {0.f, 0.f, 0.f, 0.f};
  f32x4 acc[4];
#pragma unroll
  for (int nt = 0; nt < 4; nt++) acc[nt] = zero;
  int q = lane >> 4, m16 = lane & 15;
  for (int k0 = 0; k0 < K; k0 += 32) {
    uint4 av = *(const uint4*)(Ap + k0);
    uint4 bz = {0u, 0u, 0u, 0u};
    uint4 bv = bvalid ? *(const uint4*)(Bp + k0) : bz;
    *(uint4*)&As[srow][skq] = av;
    *(uint4*)&Bs[srow][skq] = bv;
    __syncthreads();
    bf16x8 af = *(const bf16x8*)&As[wave * 16 + m16][q * 8];
#pragma unroll
    for (int nt = 0; nt < 4; nt++) {
      bf16x8 bfv = *(const bf16x8*)&Bs[nt * 16 + m16][q * 8];
      acc[nt] = __builtin_amdgcn_mfma_f32_16x16x32_bf16(af, bfv, acc[nt], 0, 0, 0);
    }
    __syncthreads();
  }
  int rbase = q * 4;
#pragma unroll
  for (int nt = 0; nt < 4; nt++) {
#pragma unroll
    for (int rr = 0; rr < 4; rr++) {
      int gm = m0 + wave * 16 + rbase + rr;
      int gn = n0 + nt * 16 + m16;
      if (gn < N) {
        float v = acc[nt][rr];
        if (BF16_OUT) {
          ((unsigned short*)Cout)[(size_t)gm * N + gn] = f2bf(v);
        } else {
          float o = v;
          if (RESID) o += resid[(size_t)gm * N + gn];
          ((float*)Cout)[(size_t)gm * N + gn] = o;
        }
      }
    }
  }
}

// ---------------- parallel activations -> act stream (f32) ----------------
// One wave per (m = t*8+b, h). act[bh][t][AST]:
// [0:64) q softmax, [64:128) k softmax, [128:192) rk softmax,
// [192:256) v, [256:320) rv, [320] sig(beta), [321] sig(rbeta), [322:352) pad.
__global__ __launch_bounds__(256) void act_kernel(const unsigned short* __restrict__ qkvb,
                                                  float* __restrict__ act) {
  int gw = blockIdx.x * 4 + (threadIdx.x >> 6);
  int l = threadIdx.x & 63;
  int m = gw >> 3, hh = gw & 7;
  int t = m >> 3, b = m & 7;
  const unsigned short* src = qkvb + (size_t)m * PROJ + hh * SEG;
  float fq = bf2f(src[l]);
  float fk = bf2f(src[64 + l]);
  float fv = bf2f(src[128 + l]);
  float fr = bf2f(src[192 + l]);
  float frv = bf2f(src[256 + l]);
  float mq = fq, mk = fk, mr = fr;
#pragma unroll
  for (int o = 32; o; o >>= 1) {
    mq = fmaxf(mq, __shfl_xor(mq, o));
    mk = fmaxf(mk, __shfl_xor(mk, o));
    mr = fmaxf(mr, __shfl_xor(mr, o));
  }
  float eq = __expf(fq - mq), ek = __expf(fk - mk), er = __expf(fr - mr);
  float sq = eq, sk = ek, sr = er;
#pragma unroll
  for (int o = 32; o; o >>= 1) {
    sq += __shfl_xor(sq, o);
    sk += __shfl_xor(sk, o);
    sr += __shfl_xor(sr, o);
  }
  int bh = b * 8 + hh;
  float* dst = act + ((size_t)bh * S_LEN + t) * AST;
  dst[l] = eq * __builtin_amdgcn_rcpf(sq);
  dst[64 + l] = ek * __builtin_amdgcn_rcpf(sk);
  dst[128 + l] = er * __builtin_amdgcn_rcpf(sr);
  dst[192 + l] = fv;
  dst[256 + l] = frv;
  if (l < 2) {
    float xv = bf2f(src[320 + l]);
    dst[320 + l] = __builtin_amdgcn_rcpf(1.f + __expf(-xv));
  }
}

// ---------------- scan: async producer/consumer waves, NO per-step barrier ----------------
// Block = 128 threads = 2 waves per (b,h). Wave0 (producer): stages act chunks via
// global_load_lds, runs the delta-rule W-scan, deposits z into a 4-chunk LDS ring,
// publishes per-chunk flags. Wave1 (consumer): polls the flag once per chunk (8 steps),
// runs the recurrent R-scan. Math bodies identical to the verified round-1 kernel.
// Rings are 4 deep; back-pressure flag keeps wave0 <=3 chunks ahead, so a slot is only
// reused 3+ chunks after the consumer finished it.
__global__ __launch_bounds__(128, 1) void scan_kernel(const float* __restrict__ act,
                                                      unsigned short* __restrict__ hs) {
  int bh = blockIdx.x;
  int b = bh >> 3, hh = bh & 7;
  int tid = threadIdx.x, l = tid & 63, w = tid >> 6;

  __shared__ __align__(16) float stage[4][CHUNK * AST];
  __shared__ __align__(16) float zring[4][CHUNK][64];
  __shared__ __align__(16) float ehb[64];
  __shared__ int flags[16];  // [0]=w0done (chunks), [8]=w1done (chunks)

  volatile int* w0done = &flags[0];
  volatile int* w1done = &flags[8];

  const char* abase = (const char*)(act + (size_t)bh * S_LEN * AST);

  if (tid == 0) { flags[0] = 0; flags[8] = 0; }
  if (w) ehb[l] = 1.f;  // softmax(h0=0) numerators -> uniform
  if (w == 0) {
    // stage chunk 0
#pragma unroll
    for (int i = 0; i < 11; i++)
      gl_lds16(abase + (size_t)i * 1024 + l * 16, (char*)&stage[0][0] + i * 1024);
  }
  __syncthreads();  // flags/ehb init visible; drains wave0's chunk-0 staging too

  f32x4 M[16];
#pragma unroll
  for (int j = 0; j < 16; j++) M[j] = (f32x4){0.f, 0.f, 0.f, 0.f};
  const f32x4 z4 = {0.f, 0.f, 0.f, 0.f};

  if (w == 0) {
    // ================= producer: W-scan =================
    for (int c = 0; c < NCH; c++) {
      // back-pressure: staging into slot (c+1)&3 overwrites chunk c-3
      if (c >= 3) {
        while (*w1done < c - 2) __builtin_amdgcn_s_sleep(2);
      }
      if (c + 1 < NCH) {
        const char* nb = abase + (size_t)(c + 1) * CB;
        char* sb = (char*)&stage[(c + 1) & 3][0];
#pragma unroll
        for (int i = 0; i < 11; i++)
          gl_lds16(nb + (size_t)i * 1024 + l * 16, sb + i * 1024);
        asm volatile("s_waitcnt vmcnt(11)" ::: "memory");  // chunk c's staging done
      } else {
        asm volatile("s_waitcnt vmcnt(0)" ::: "memory");
      }
      const float* cb = &stage[c & 3][0];
      float* zc = &zring[c & 3][0][0];
#pragma unroll
      for (int s = 0; s < CHUNK; s++) {
        const float* stf = cb + s * AST;
        const f32x4* st4 = (const f32x4*)stf;
        // ---- vold = W.k; fused W += coef*k, z = W.q ----
        float cv = stf[192 + l];
        f32x4 kk[16];
#pragma unroll
        for (int j = 0; j < 16; j++) kk[j] = st4[16 + j];  // k
        f32x4 a0 = z4, a1 = z4, a2 = z4, a3 = z4;
#pragma unroll
        for (int j = 0; j < 16; j += 4) {
          a0 += M[j] * kk[j];
          a1 += M[j + 1] * kk[j + 1];
          a2 += M[j + 2] * kk[j + 2];
          a3 += M[j + 3] * kk[j + 3];
        }
        f32x4 vo = (a0 + a1) + (a2 + a3);
        float vold = (vo.x + vo.y) + (vo.z + vo.w);
        float bt = stf[320];
        float coef = bt * (cv - vold);
        f32x4 c4 = {coef, coef, coef, coef};
        a0 = a1 = a2 = a3 = z4;
#pragma unroll
        for (int j = 0; j < 16; j += 4) {
          M[j] += c4 * kk[j];         a0 += M[j] * st4[j];
          M[j + 1] += c4 * kk[j + 1]; a1 += M[j + 1] * st4[j + 1];
          M[j + 2] += c4 * kk[j + 2]; a2 += M[j + 2] * st4[j + 2];
          M[j + 3] += c4 * kk[j + 3]; a3 += M[j + 3] * st4[j + 3];
        }
        vo = (a0 + a1) + (a2 + a3);
        zc[s * 64 + l] = (vo.x + vo.y) + (vo.z + vo.w);
      }
      asm volatile("s_waitcnt lgkmcnt(0)" ::: "memory");  // z writes retired
      *w0done = c + 1;
    }
  } else {
    // ================= consumer: R-scan =================
    unsigned short* hdst = hs + (size_t)b * 512 + hh * 64 + l;
    for (int c = 0; c < NCH; c++) {
      while (*w0done < c + 1) __builtin_amdgcn_s_sleep(2);  // chunk c staged + z ready
      const float* cb = &stage[c & 3][0];
      const float* zc = &zring[c & 3][0][0];
#pragma unroll
      for (int s = 0; s < CHUNK; s++) {
        const float* stf = cb + s * AST;
        const f32x4* st4 = (const f32x4*)stf;
        float z = zc[s * 64 + l];  // issue early; latency hides under matvec
        // ---- rvold = R.rk; fused R += rcoef*rk, hp = R.eh, sm = sum(eh) ----
        float cv = stf[256 + l];
        f32x4 kk[16];
#pragma unroll
        for (int j = 0; j < 16; j++) kk[j] = st4[32 + j];  // rk
        f32x4 a0 = z4, a1 = z4, a2 = z4, a3 = z4;
#pragma unroll
        for (int j = 0; j < 16; j += 4) {
          a0 += M[j] * kk[j];
          a1 += M[j + 1] * kk[j + 1];
          a2 += M[j + 2] * kk[j + 2];
          a3 += M[j + 3] * kk[j + 3];
        }
        f32x4 vo = (a0 + a1) + (a2 + a3);
        float rvold = (vo.x + vo.y) + (vo.z + vo.w);
        float rb = stf[321];
        float rcoef = rb * (cv - rvold);
        f32x4 c4 = {rcoef, rcoef, rcoef, rcoef};
        const f32x4* e4 = (const f32x4*)ehb;
        f32x4 s0 = z4, s1 = z4, s2v = z4, s3 = z4;
        a0 = a1 = a2 = a3 = z4;
#pragma unroll
        for (int j = 0; j < 16; j += 4) {
          f32x4 e0 = e4[j], e1 = e4[j + 1], e2 = e4[j + 2], e3 = e4[j + 3];
          M[j] += c4 * kk[j];         a0 += M[j] * e0;       s0 += e0;
          M[j + 1] += c4 * kk[j + 1]; a1 += M[j + 1] * e1;   s1 += e1;
          M[j + 2] += c4 * kk[j + 2]; a2 += M[j + 2] * e2;   s2v += e2;
          M[j + 3] += c4 * kk[j + 3]; a3 += M[j + 3] * e3;   s3 += e3;
        }
        f32x4 ho = (a0 + a1) + (a2 + a3);
        f32x4 so = (s0 + s1) + (s2v + s3);
        float hp = (ho.x + ho.y) + (ho.z + ho.w);
        float sm = (so.x + so.y) + (so.z + so.w);
        float h = z + hp * __builtin_amdgcn_rcpf(sm);
        hdst[(size_t)(c * CHUNK + s) * (BSZ * 512)] = f2bf(h);
        // shift-invariant: exp(h-20) keeps qh = eh/sum exact, guards overflow.
        // same-wave DS ordering makes it visible to next step's e4 reads.
        ehb[l] = __expf(h - 20.f);
      }
      asm volatile("s_waitcnt lgkmcnt(0)" ::: "memory");  // all chunk-c reads retired
      *w1done = c + 1;
    }
  }
}

extern "C" void kernel_launch(void* const* d_in, const int* in_sizes, int n_in,
                              void* d_out, int out_size, void* d_ws, size_t ws_size,
                              hipStream_t stream) {
  const float* x = (const float*)d_in[0];
  const float* W_slow = (const float*)d_in[1];
  const float* W_out = (const float*)d_in[2];
  const float* gamma = (const float*)d_in[3];
  const float* beta = (const float*)d_in[4];

  char* ws = (char*)d_ws;
  size_t off = 0;
  unsigned short* normed = (unsigned short*)(ws + off); off += (size_t)4096 * 512 * 2;
  unsigned short* Wslow_b = (unsigned short*)(ws + off); off += (size_t)PROJ * 512 * 2;
  unsigned short* Wout_b = (unsigned short*)(ws + off); off += (size_t)512 * 512 * 2;
  unsigned short* qkvb = (unsigned short*)(ws + off); off += (size_t)4096 * PROJ * 2;
  float* act = (float*)(ws + off); off += (size_t)64 * S_LEN * AST * 4;
  unsigned short* hsb = normed;  // normed is dead after gemm1; reuse for hs

  hipLaunchKernelGGL(ln_kernel, dim3(1024), dim3(256), 0, stream, x, gamma, beta, normed);
  hipLaunchKernelGGL(cast_kernel, dim3(512), dim3(256), 0, stream, W_slow, Wslow_b, PROJ * 512);
  hipLaunchKernelGGL(cast_kernel, dim3(256), dim3(256), 0, stream, W_out, Wout_b, 512 * 512);
  hipLaunchKernelGGL((gemm_bt<1, 0>), dim3((PROJ + 63) / 64, 4096 / 64), dim3(256), 0, stream,
                     normed, Wslow_b, (void*)qkvb, (const float*)nullptr, 4096, PROJ, 512);
  hipLaunchKernelGGL(act_kernel, dim3(8192), dim3(256), 0, stream, qkvb, act);
  hipLaunchKernelGGL(scan_kernel, dim3(64), dim3(128), 0, stream, act, hsb);
  hipLaunchKernelGGL((gemm_bt<0, 1>), dim3(512 / 64, 4096 / 64), dim3(256), 0, stream,
                     hsb, Wout_b, d_out, x, 4096, 512, 512);
}